// Round 4
// baseline (57.477 us; speedup 1.0000x reference)
//
#include <hip/hip_runtime.h>

// Problem constants (fixed by reference shapes)
#define NB 2        // batch
#define BB 257      // bins
#define PB 256      // centers = bins-1
#define LL 16       // patches per image (4x4)
#define QQ 12544    // points per patch (112*112)
#define KP 112      // patch size
#define WIMG 448    // image width
#define SPLIT 7     // Q-slices per patch; QS = 12544/7 = 1792 = 7*256 exactly
#define QS 1792
#define VPT 7       // points per thread (exact)
#define NPATCH (NB*LL)          // 32
#define NBLK (NPATCH*SPLIT)     // 224 blocks
#define BIGV 1e10f
#define SENT_LO (-2e18f)
#define SENT_HI ( 2e18f)

// ws layout (u32 slots). Per (patch,slice): lo[256] | hi[256] | sumY | cnt
#define SL_STRIDE 514
#define PP_BASE   (NBLK*SL_STRIDE)   // 32 floats: per-patch results
#define PCTR_BASE (PP_BASE + NPATCH) // 32 patch tickets (memset to 0 each call)
#define GCTR_BASE (PCTR_BASE + NPATCH) // 1 global ticket (memset to 0 each call)

// monotone float<->uint mapping: uint order == float order
__device__ __forceinline__ unsigned encf(float f) {
    unsigned u = __float_as_uint(f);
    return (u >> 31) ? ~u : (u | 0x80000000u);
}
__device__ __forceinline__ float decf(unsigned e) {
    return __uint_as_float((e >> 31) ? (e & 0x7fffffffu) : ~e);
}
__device__ __forceinline__ unsigned umaxu(unsigned a, unsigned b){ return a > b ? a : b; }
__device__ __forceinline__ unsigned uminu(unsigned a, unsigned b){ return a < b ? a : b; }

__global__ __launch_bounds__(256) void chamfer_fused(const float* __restrict__ bins,
                                                     const float* __restrict__ img,
                                                     unsigned* __restrict__ ws,
                                                     float* __restrict__ out) {
    __shared__ __align__(16) float tmp[PB];
    __shared__ __align__(16) float cs[PB];
    __shared__ unsigned lop[PB], hih[PB];
    __shared__ float rs[4], rc[4];
    __shared__ int flag;

    float* wsf = (float*)ws;
    const int bid = blockIdx.x;
    const int g  = bid / SPLIT;          // patch id 0..31
    const int sl = bid % SPLIT;
    const int n = g / LL, l = g % LL;
    const int t = threadIdx.x;
    const int wid = t >> 6, lane = t & 63;
    const unsigned ELO = encf(SENT_LO), EHI = encf(SENT_HI);

    // ---- centers + rank sort (redundant per block; cheap) ----
    float c;
    {
        float b0 = bins[(n*BB + t    )*LL + l];
        float b1 = bins[(n*BB + t + 1)*LL + l];
        c = 0.5f * (b0 + b1);
    }
    tmp[t] = c;
    lop[t] = ELO;
    hih[t] = EHI;
    __syncthreads();
    {
        int rank = 0;
        const float4* t4 = reinterpret_cast<const float4*>(tmp);
        #pragma unroll 16
        for (int j = 0; j < 64; ++j) {
            float4 q = t4[j];
            int b = 4*j;
            rank += (q.x < c || (q.x == c && (b+0) < t)) ? 1 : 0;
            rank += (q.y < c || (q.y == c && (b+1) < t)) ? 1 : 0;
            rank += (q.z < c || (q.z == c && (b+2) < t)) ? 1 : 0;
            rank += (q.w < c || (q.w == c && (b+3) < t)) ? 1 : 0;
        }
        cs[rank] = c;
    }
    __syncthreads();

    // ---- load my 7 points; 7 independent binary-search chains (ILP) ----
    const float* pimg = img + n*WIMG*WIMG + (l >> 2)*KP*WIMG + (l & 3)*KP;
    float v[VPT];
    int   u[VPT];
    #pragma unroll
    for (int k = 0; k < VPT; ++k) {
        int q = sl*QS + t + k*256;
        int ki = q / KP, kj = q - ki*KP;
        v[k] = pimg[ki*WIMG + kj];
    }
    #pragma unroll
    for (int k = 0; k < VPT; ++k) {
        float x = v[k];
        int uu = 0;
        #pragma unroll
        for (int stp = 128; stp; stp >>= 1)
            uu += (cs[uu + stp - 1] < x) ? stp : 0;
        uu += (cs[PB-1] < x) ? 1 : 0;
        u[k] = uu;
    }

    // ---- chamfer y->x partial sums + lo/hi candidate LDS atomics ----
    float ls = 0.f, lc = 0.f;
    #pragma unroll
    for (int k = 0; k < VPT; ++k) {
        float x = v[k];
        if (x > 0.f) {
            int uu = u[k];
            float dmin = BIGV;
            if (uu > 0)  { float d = x - cs[uu-1]; dmin = d*d;              atomicMin(&hih[uu-1], encf(x)); }
            if (uu < PB) { float d = cs[uu] - x;   dmin = fminf(dmin, d*d); atomicMax(&lop[uu],  encf(x)); }
            ls += dmin;
            lc += 1.f;
        }
    }
    #pragma unroll
    for (int m = 32; m; m >>= 1) { ls += __shfl_xor(ls, m); lc += __shfl_xor(lc, m); }
    if (lane == 0) { rs[wid] = ls; rc[wid] = lc; }
    __syncthreads();

    // ---- publish this slice's results (plain stores, disjoint region) ----
    unsigned* slb = ws + (unsigned)(g*SPLIT + sl)*SL_STRIDE;
    slb[t]      = lop[t];
    slb[PB + t] = hih[t];
    if (t == 0) {
        wsf[(g*SPLIT + sl)*SL_STRIDE + 2*PB    ] = rs[0]+rs[1]+rs[2]+rs[3];
        wsf[(g*SPLIT + sl)*SL_STRIDE + 2*PB + 1] = rc[0]+rc[1]+rc[2]+rc[3];
    }

    // ---- patch ticket: counters memset to 0 each call -> last arriver wins ----
    __threadfence();
    __syncthreads();
    if (t == 0) {
        unsigned old = atomicAdd(ws + PCTR_BASE + g, 1u);
        flag = (old == SPLIT - 1u) ? 1 : 0;
    }
    __syncthreads();
    if (!flag) return;
    __threadfence();

    // ---- patch final: merge 7 slices, scan, chamfer x->y ----
    unsigned lo = ELO, hi = EHI;
    const unsigned* pb0 = ws + (unsigned)(g*SPLIT)*SL_STRIDE;
    #pragma unroll
    for (int s = 0; s < SPLIT; ++s) {
        lo = umaxu(lo, pb0[s*SL_STRIDE + t]);
        hi = uminu(hi, pb0[s*SL_STRIDE + PB + t]);
    }
    __syncthreads();
    lop[t] = lo; hih[t] = hi;
    __syncthreads();
    #pragma unroll
    for (int d = 1; d < PB; d <<= 1) {
        unsigned a  = lop[t], b = hih[t];
        unsigned al = (t >= d)     ? lop[t - d] : ELO;
        unsigned bh = (t + d < PB) ? hih[t + d] : EHI;
        __syncthreads();
        lop[t] = umaxu(a, al);
        hih[t] = uminu(b, bh);
        __syncthreads();
    }
    float da = cs[t] - decf(lop[t]);
    float db = decf(hih[t]) - cs[t];
    float term = fminf(da*da, db*db);
    #pragma unroll
    for (int m = 32; m; m >>= 1) term += __shfl_xor(term, m);
    if (lane == 0) rs[wid] = term;
    __syncthreads();

    if (t == 0) {
        float chxsum = rs[0]+rs[1]+rs[2]+rs[3];
        float sy = 0.f, cy = 0.f;
        #pragma unroll
        for (int s = 0; s < SPLIT; ++s) {
            sy += wsf[(g*SPLIT + s)*SL_STRIDE + 2*PB    ];
            cy += wsf[(g*SPLIT + s)*SL_STRIDE + 2*PB + 1];
        }
        float chx = chxsum * (1.0f / PB);
        float chy = sy / fmaxf(cy, 1.f);
        wsf[PP_BASE + g] = (cy > 0.5f) ? (chx + chy) : 0.f;
        __threadfence();
        unsigned old = atomicAdd(ws + GCTR_BASE, 1u);
        flag = (old == NPATCH - 1u) ? 1 : 0;
    }
    __syncthreads();
    if (!flag) return;
    __threadfence();

    // ---- global final: deterministic fixed-tree mean of 32 patch values ----
    if (t < 64) {
        float val = (lane < NPATCH) ? wsf[PP_BASE + lane] : 0.f;
        #pragma unroll
        for (int m = 32; m; m >>= 1) val += __shfl_xor(val, m);
        if (lane == 0) out[0] = val * (1.0f / NPATCH);
    }
}

extern "C" void kernel_launch(void* const* d_in, const int* in_sizes, int n_in,
                              void* d_out, int out_size, void* d_ws, size_t ws_size,
                              hipStream_t stream) {
    const float* bins = (const float*)d_in[0];
    const float* img  = (const float*)d_in[1];
    unsigned* ws = (unsigned*)d_ws;
    float* out = (float*)d_out;
    (void)in_sizes; (void)n_in; (void)out_size; (void)ws_size;

    // Zero the 33 ticket counters every call (graph-capture-safe memset node).
    hipMemsetAsync(ws + PCTR_BASE, 0, (NPATCH + 1) * sizeof(unsigned), stream);
    hipLaunchKernelGGL(chamfer_fused, dim3(NBLK), dim3(256), 0, stream, bins, img, ws, out);
}

// Round 5
// 25.856 us; speedup vs baseline: 2.2230x; 2.2230x over previous
//
#include <hip/hip_runtime.h>

// Problem constants (fixed by reference shapes)
#define NB 2        // batch
#define BB 257      // bins
#define PB 256      // centers = bins-1
#define LL 16       // patches per image (4x4)
#define QQ 12544    // points per patch (112*112)
#define KP 112      // patch size
#define WIMG 448    // image width
#define NPATCH (NB*LL)   // 32
#define VPT 12           // 1024*12 = 12288 points; +256 tail
#define BIGV 1e10f
#define SENT_LO (-2e18f)
#define SENT_HI ( 2e18f)

// monotone float<->uint mapping: uint order == float order
__device__ __forceinline__ unsigned encf(float f) {
    unsigned u = __float_as_uint(f);
    return (u >> 31) ? ~u : (u | 0x80000000u);
}
__device__ __forceinline__ float decf(unsigned e) {
    return __uint_as_float((e >> 31) ? (e & 0x7fffffffu) : ~e);
}
__device__ __forceinline__ unsigned umaxu(unsigned a, unsigned b){ return a > b ? a : b; }
__device__ __forceinline__ unsigned uminu(unsigned a, unsigned b){ return a < b ? a : b; }
__device__ __forceinline__ float nn_term(float c, unsigned lo, unsigned hi) {
    float a = c - decf(lo);
    float b = decf(hi) - c;
    return fminf(a*a, b*b);
}

// ---- kernel 1: one block per patch; everything in LDS; writes one float ----
__global__ __launch_bounds__(1024) void patch_chamfer(const float* __restrict__ bins,
                                                      const float* __restrict__ img,
                                                      float* __restrict__ wsf) {
    __shared__ float bt[BB];
    __shared__ __align__(16) float cu[PB];
    __shared__ __align__(16) float cs[PB];
    __shared__ __align__(16) unsigned lop[PB];
    __shared__ __align__(16) unsigned hih[PB];
    __shared__ float rs[16], rc[16];

    const int g = blockIdx.x;            // patch id 0..31
    const int n = g / LL, l = g % LL;
    const int t = threadIdx.x;
    const int wid = t >> 6, lane = t & 63;
    const unsigned ELO = encf(SENT_LO), EHI = encf(SENT_HI);

    if (t < PB) { lop[t] = ELO; hih[t] = EHI; }
    if (t < BB) bt[t] = bins[(n*BB + t)*LL + l];
    __syncthreads();

    float c = 0.f;
    if (t < PB) { c = 0.5f * (bt[t] + bt[t+1]); cu[t] = c; }
    __syncthreads();

    // rank sort (stable via index tie-break) -> cs sorted ascending
    if (t < PB) {
        int rank = 0;
        const float4* t4 = reinterpret_cast<const float4*>(cu);
        #pragma unroll 16
        for (int j = 0; j < 64; ++j) {
            float4 q = t4[j];
            int b = 4*j;
            rank += (q.x < c || (q.x == c && (b+0) < t)) ? 1 : 0;
            rank += (q.y < c || (q.y == c && (b+1) < t)) ? 1 : 0;
            rank += (q.z < c || (q.z == c && (b+2) < t)) ? 1 : 0;
            rank += (q.w < c || (q.w == c && (b+3) < t)) ? 1 : 0;
        }
        cs[rank] = c;
    }
    __syncthreads();

    // ---- load my 12 (+1 tail) points ----
    const float* pimg = img + n*WIMG*WIMG + (l >> 2)*KP*WIMG + (l & 3)*KP;
    float v[VPT]; int u[VPT];
    #pragma unroll
    for (int k = 0; k < VPT; ++k) {
        int q = k*1024 + t, ki = q / KP, kj = q - ki*KP;
        v[k] = pimg[ki*WIMG + kj];
    }
    const bool tail = (t < 256);
    float vt = 0.f; int ut = 0;
    if (tail) {
        int q = VPT*1024 + t, ki = q / KP, kj = q - ki*KP;
        vt = pimg[ki*WIMG + kj];
    }

    // ---- 12 independent branchless lower_bound chains (ILP) ----
    #pragma unroll
    for (int k = 0; k < VPT; ++k) {
        float x = v[k]; int uu = 0;
        #pragma unroll
        for (int stp = 128; stp; stp >>= 1)
            uu += (cs[uu + stp - 1] < x) ? stp : 0;
        uu += (cs[PB-1] < x) ? 1 : 0;
        u[k] = uu;
    }
    if (tail) {
        float x = vt; int uu = 0;
        #pragma unroll
        for (int stp = 128; stp; stp >>= 1)
            uu += (cs[uu + stp - 1] < x) ? stp : 0;
        uu += (cs[PB-1] < x) ? 1 : 0;
        ut = uu;
    }

    // ---- chamfer y->x partials + lo/hi candidate LDS atomics ----
    float ls = 0.f, lc = 0.f;
    auto contrib = [&](float x, int uu) {
        if (x > 0.f) {
            float dmin = BIGV;
            if (uu > 0)  { float d = x - cs[uu-1]; dmin = d*d;              atomicMin(&hih[uu-1], encf(x)); }
            if (uu < PB) { float d = cs[uu] - x;   dmin = fminf(dmin, d*d); atomicMax(&lop[uu],  encf(x)); }
            ls += dmin;
            lc += 1.f;
        }
    };
    #pragma unroll
    for (int k = 0; k < VPT; ++k) contrib(v[k], u[k]);
    if (tail) contrib(vt, ut);

    #pragma unroll
    for (int m = 32; m; m >>= 1) { ls += __shfl_xor(ls, m); lc += __shfl_xor(lc, m); }
    if (lane == 0) { rs[wid] = ls; rc[wid] = lc; }
    __syncthreads();   // publishes rs/rc AND all LDS atomics

    // ---- wave 0: prefix-max / suffix-min scan + chamfer x->y + patch value ----
    if (wid == 0) {
        uint4  lp = reinterpret_cast<const uint4*>(lop)[lane];
        uint4  hp = reinterpret_cast<const uint4*>(hih)[lane];
        float4 cv = reinterpret_cast<const float4*>(cs)[lane];

        unsigned p0 = lp.x, p1 = umaxu(p0, lp.y), p2 = umaxu(p1, lp.z), p3 = umaxu(p2, lp.w);
        unsigned inc = p3;
        #pragma unroll
        for (int d = 1; d < 64; d <<= 1) {
            unsigned o = __shfl_up(inc, d);
            if (lane >= d) inc = umaxu(inc, o);
        }
        unsigned ex = __shfl_up(inc, 1);
        if (lane == 0) ex = ELO;
        unsigned lo0 = umaxu(ex,p0), lo1 = umaxu(ex,p1), lo2 = umaxu(ex,p2), lo3 = umaxu(ex,p3);

        unsigned s3 = hp.w, s2 = uminu(hp.z, s3), s1 = uminu(hp.y, s2), s0 = uminu(hp.x, s1);
        unsigned incs = s0;
        #pragma unroll
        for (int d = 1; d < 64; d <<= 1) {
            unsigned o = __shfl_down(incs, d);
            if (lane + d < 64) incs = uminu(incs, o);
        }
        unsigned exh = __shfl_down(incs, 1);
        if (lane == 63) exh = EHI;
        unsigned hi0 = uminu(exh,s0), hi1 = uminu(exh,s1), hi2 = uminu(exh,s2), hi3 = uminu(exh,s3);

        float sum = nn_term(cv.x, lo0, hi0) + nn_term(cv.y, lo1, hi1)
                  + nn_term(cv.z, lo2, hi2) + nn_term(cv.w, lo3, hi3);
        #pragma unroll
        for (int m = 32; m; m >>= 1) sum += __shfl_xor(sum, m);

        if (lane == 0) {
            float sy = 0.f, cy = 0.f;
            #pragma unroll
            for (int i = 0; i < 16; ++i) { sy += rs[i]; cy += rc[i]; }
            float chx = sum * (1.0f / PB);
            float chy = sy / fmaxf(cy, 1.f);
            wsf[g] = (cy > 0.5f) ? (chx + chy) : 0.f;
        }
    }
}

// ---- kernel 2: deterministic fixed-tree mean of 32 patch values ----
__global__ __launch_bounds__(64) void final_mean(const float* __restrict__ wsf,
                                                 float* __restrict__ out) {
    const int lane = threadIdx.x;
    float val = (lane < NPATCH) ? wsf[lane] : 0.f;
    #pragma unroll
    for (int m = 32; m; m >>= 1) val += __shfl_xor(val, m);
    if (lane == 0) out[0] = val * (1.0f / NPATCH);
}

extern "C" void kernel_launch(void* const* d_in, const int* in_sizes, int n_in,
                              void* d_out, int out_size, void* d_ws, size_t ws_size,
                              hipStream_t stream) {
    const float* bins = (const float*)d_in[0];
    const float* img  = (const float*)d_in[1];
    float* wsf = (float*)d_ws;
    float* out = (float*)d_out;
    (void)in_sizes; (void)n_in; (void)out_size; (void)ws_size;

    hipLaunchKernelGGL(patch_chamfer, dim3(NPATCH), dim3(1024), 0, stream, bins, img, wsf);
    hipLaunchKernelGGL(final_mean,    dim3(1),      dim3(64),   0, stream, wsf, out);
}